// Round 1
// baseline (1436.764 us; speedup 1.0000x reference)
//
#include <hip/hip_runtime.h>

constexpr int NB  = 8;    // n_bundles
constexpr int BD  = 16;   // bundle_dim
constexpr int TD  = 128;  // total dim
constexpr int HID = 64;   // hidden

__device__ __forceinline__ float gelu_exact(float x) {
    return 0.5f * x * (1.0f + erff(x * 0.7071067811865476f));
}

__global__ __launch_bounds__(256, 2)
void soft_equiv_kernel(const float* __restrict__ z,
                       const float* __restrict__ W1,
                       const float* __restrict__ b1,
                       const float* __restrict__ W2,
                       const float* __restrict__ b2,
                       const float* __restrict__ W3,
                       const float* __restrict__ mixW,
                       const float* __restrict__ gate_bias,
                       float* __restrict__ out,
                       int B)
{
    const int row = blockIdx.x * 256 + threadIdx.x;
    if (row >= B) return;

    const float* zrow = z + (size_t)row * TD;
    float zr[TD];
#pragma unroll
    for (int q = 0; q < TD / 4; ++q) {
        const float4 v = reinterpret_cast<const float4*>(zrow)[q];
        zr[4*q+0] = v.x; zr[4*q+1] = v.y; zr[4*q+2] = v.z; zr[4*q+3] = v.w;
    }

    // ---- per-bundle norms (+1e-8, matching reference) ----
    float nrm[NB];
#pragma unroll
    for (int j = 0; j < NB; ++j) {
        float s0 = 0.f, s1 = 0.f, s2 = 0.f, s3 = 0.f;
#pragma unroll
        for (int k = 0; k < BD; k += 4) {
            const float a = zr[j*BD+k+0], b_ = zr[j*BD+k+1];
            const float c = zr[j*BD+k+2], d_ = zr[j*BD+k+3];
            s0 = fmaf(a, a, s0); s1 = fmaf(b_, b_, s1);
            s2 = fmaf(c, c, s2); s3 = fmaf(d_, d_, s3);
        }
        nrm[j] = sqrtf((s0 + s1) + (s2 + s3)) + 1e-8f;
    }

    // ---- layer 1: [8] -> [64], exact GELU ----
    // fully unrolled: h1[i] must be a compile-time register index
    float h1[HID];
#pragma unroll
    for (int i = 0; i < HID; ++i) {
        float a = b1[i];
#pragma unroll
        for (int j = 0; j < NB; ++j) a = fmaf(W1[i*NB + j], nrm[j], a);
        h1[i] = gelu_exact(a);
    }

    // ---- layer 2: [64] -> [64], GELU, with layer-3 accumulation fused ----
    // i-loop rolled (only W2/W3 indices depend on i -> uniform scalar loads);
    // all register-array indices inside are static.
    float acc3[NB];
#pragma unroll
    for (int j = 0; j < NB; ++j) acc3[j] = 0.f;
#pragma unroll 1
    for (int i = 0; i < HID; ++i) {
        float a0 = b2[i], a1 = 0.f, a2 = 0.f, a3 = 0.f;
#pragma unroll
        for (int j = 0; j < HID; j += 4) {
            a0 = fmaf(W2[i*HID + j + 0], h1[j + 0], a0);
            a1 = fmaf(W2[i*HID + j + 1], h1[j + 1], a1);
            a2 = fmaf(W2[i*HID + j + 2], h1[j + 2], a2);
            a3 = fmaf(W2[i*HID + j + 3], h1[j + 3], a3);
        }
        const float g = gelu_exact((a0 + a1) + (a2 + a3));
#pragma unroll
        for (int j = 0; j < NB; ++j) acc3[j] = fmaf(W3[j*HID + i], g, acc3[j]);
    }

    // ---- softplus scales (fold the +1 from the residual) & sigmoid gates ----
    float s1p[NB], gate[NB];
#pragma unroll
    for (int j = 0; j < NB; ++j) {
        const float x  = acc3[j];
        const float sp = fmaxf(x, 0.f) + log1pf(expf(-fabsf(x)));  // stable softplus
        s1p[j]  = 1.0f + sp;
        gate[j] = 1.0f / (1.0f + expf(-gate_bias[j]));
    }

    // ---- mixed = z-row times 128x128 mixW matrix, fused epilogue ----
    // mixW[i][j][d][k] flat = i*2048 + j*256 + d*16 + k
    float* orow = out + (size_t)row * TD;
#pragma unroll 1
    for (int i = 0; i < NB; ++i) {
        const float* Mi = mixW + (size_t)i * (NB * BD * BD);
        const float gi = gate[i], si = s1p[i];
#pragma unroll 1
        for (int d4 = 0; d4 < BD / 4; ++d4) {
            float m0 = 0.f, m1 = 0.f, m2 = 0.f, m3 = 0.f;
#pragma unroll
            for (int j = 0; j < NB; ++j) {
                const float* Mij = Mi + j*(BD*BD) + d4*4*BD;
#pragma unroll
                for (int k = 0; k < BD; ++k) {
                    const float zv = zr[j*BD + k];
                    m0 = fmaf(Mij[0*BD + k], zv, m0);
                    m1 = fmaf(Mij[1*BD + k], zv, m1);
                    m2 = fmaf(Mij[2*BD + k], zv, m2);
                    m3 = fmaf(Mij[3*BD + k], zv, m3);
                }
            }
            const int ob = i*BD + d4*4;
            float4 st;
            st.x = fmaf(zr[ob + 0], si, gi * m0);
            st.y = fmaf(zr[ob + 1], si, gi * m1);
            st.z = fmaf(zr[ob + 2], si, gi * m2);
            st.w = fmaf(zr[ob + 3], si, gi * m3);
            reinterpret_cast<float4*>(orow)[i*4 + d4] = st;
        }
    }
}

extern "C" void kernel_launch(void* const* d_in, const int* in_sizes, int n_in,
                              void* d_out, int out_size, void* d_ws, size_t ws_size,
                              hipStream_t stream) {
    const float* z    = (const float*)d_in[0];
    const float* W1   = (const float*)d_in[1];
    const float* b1   = (const float*)d_in[2];
    const float* W2   = (const float*)d_in[3];
    const float* b2   = (const float*)d_in[4];
    const float* W3   = (const float*)d_in[5];
    const float* mixW = (const float*)d_in[6];
    const float* gb   = (const float*)d_in[7];
    float* out = (float*)d_out;

    const int B = in_sizes[0] / TD;
    const int grid = (B + 255) / 256;
    soft_equiv_kernel<<<grid, 256, 0, stream>>>(z, W1, b1, W2, b2, W3, mixW, gb, out, B);
}

// Round 2
// 432.690 us; speedup vs baseline: 3.3205x; 3.3205x over previous
//
#include <hip/hip_runtime.h>

constexpr int NB  = 8;
constexpr int BD  = 16;
constexpr int TD  = 128;
constexpr int HID = 64;
constexpr int ROWS = 128;   // rows per block

typedef __attribute__((ext_vector_type(8))) short bf16x8;
typedef __attribute__((ext_vector_type(4))) float f32x4;

__device__ __forceinline__ float gelu_exact(float x) {
    return 0.5f * x * (1.0f + erff(x * 0.7071067811865476f));
}
// fp32 -> bf16 bits, round-to-nearest-even (finite inputs)
__device__ __forceinline__ short f2bf(float f) {
    uint32_t u = __float_as_uint(f);
    uint32_t r = (u + 0x7FFFu + ((u >> 16) & 1u)) >> 16;
    return (short)r;
}

__global__ __launch_bounds__(256, 2)
void soft_equiv(const float* __restrict__ z,  const float* __restrict__ W1,
                const float* __restrict__ b1, const float* __restrict__ W2,
                const float* __restrict__ b2, const float* __restrict__ W3,
                const float* __restrict__ mixW, const float* __restrict__ gb,
                float* __restrict__ out)
{
    // z tile, swizzled: row r, global 16B-chunk q stored at word r*128 + ((q ^ (r&7))<<2)
    __shared__ float zs[ROWS * TD];           // 64 KB
    __shared__ float pscr[2 * ROWS * 9];      // layer-2 partials (padded stride 9)
    __shared__ float sca[ROWS * 9];           // 1+softplus(scales) per row/bundle

    const int t    = threadIdx.x;
    const int lane = t & 63;
    const int w    = t >> 6;        // wave 0..3 -> owns cols [32w, 32w+32)
    const int hi   = lane >> 4;     // 0..3
    const int lo   = lane & 15;
    const size_t row0 = (size_t)blockIdx.x * ROWS;
    const float* ztile = z + row0 * TD;

    // ---- B fragments: Wm[c][f] = mixW[i,j,d,k], c=i*16+d, f=j*16+k; bf16, whole kernel ----
    bf16x8 bfr[2][4];
#pragma unroll
    for (int n = 0; n < 2; ++n) {
        const int col = w * 32 + n * 16 + lo;
#pragma unroll
        for (int kk = 0; kk < 4; ++kk) {
            const int k0 = kk * 32 + hi * 8;
            const float* p = mixW + (col >> 4) * 2048 + (k0 >> 4) * 256
                                  + (col & 15) * 16 + (k0 & 15);
            const float4 x = *(const float4*)p;
            const float4 y = *(const float4*)(p + 4);
            bf16x8 f;
            f[0]=f2bf(x.x); f[1]=f2bf(x.y); f[2]=f2bf(x.z); f[3]=f2bf(x.w);
            f[4]=f2bf(y.x); f[5]=f2bf(y.y); f[6]=f2bf(y.z); f[7]=f2bf(y.w);
            bfr[n][kk] = f;
        }
    }

    // ---- phase 0: coalesced global -> swizzled LDS ----
#pragma unroll
    for (int i = 0; i < 16; ++i) {
        const int f = t + i * 256;                // float4 index in 128x128 tile
        const float4 v = *(const float4*)(ztile + 4 * f);
        const int r = f >> 5, c = f & 31;
        *(float4*)&zs[r * TD + ((c ^ (r & 7)) << 2)] = v;
    }
    __syncthreads();

    // ---- MLP: 2 threads per row (split over layer-2 outputs) ----
    const int r    = t & 127;
    const int half = t >> 7;
    const int sxr  = r & 7;

    float nsq[NB];
#pragma unroll
    for (int j = 0; j < NB; ++j) nsq[j] = 0.f;
#pragma unroll
    for (int q = 0; q < 32; ++q) {               // global chunk order -> static bundle idx
        const float4 v = *(const float4*)&zs[r * TD + ((q ^ sxr) << 2)];
        const int b = q >> 2;
        nsq[b] = fmaf(v.x, v.x, nsq[b]); nsq[b] = fmaf(v.y, v.y, nsq[b]);
        nsq[b] = fmaf(v.z, v.z, nsq[b]); nsq[b] = fmaf(v.w, v.w, nsq[b]);
    }
    float nrm[NB];
#pragma unroll
    for (int j = 0; j < NB; ++j) nrm[j] = sqrtf(nsq[j]) + 1e-8f;

    float h1[HID];
#pragma unroll
    for (int i = 0; i < HID; ++i) {
        float a = b1[i];
#pragma unroll
        for (int j = 0; j < NB; ++j) a = fmaf(W1[i * NB + j], nrm[j], a);
        h1[i] = gelu_exact(a);
    }

    float acc3[NB];
#pragma unroll
    for (int j = 0; j < NB; ++j) acc3[j] = 0.f;
    const int ibase = half * 32;
#pragma unroll 2
    for (int ii = 0; ii < 32; ++ii) {
        const int i = ibase + ii;
        const float* w2r = W2 + i * HID;
        float a0 = b2[i], a1 = 0.f, a2 = 0.f, a3 = 0.f;
#pragma unroll
        for (int j = 0; j < HID; j += 4) {
            a0 = fmaf(w2r[j + 0], h1[j + 0], a0);
            a1 = fmaf(w2r[j + 1], h1[j + 1], a1);
            a2 = fmaf(w2r[j + 2], h1[j + 2], a2);
            a3 = fmaf(w2r[j + 3], h1[j + 3], a3);
        }
        const float g = gelu_exact((a0 + a1) + (a2 + a3));
#pragma unroll
        for (int j = 0; j < NB; ++j) acc3[j] = fmaf(W3[j * HID + i], g, acc3[j]);
    }
#pragma unroll
    for (int j = 0; j < NB; ++j) pscr[(half * ROWS + r) * 9 + j] = acc3[j];
    __syncthreads();

    if (t < ROWS) {
#pragma unroll
        for (int j = 0; j < NB; ++j) {
            const float x  = pscr[r * 9 + j] + pscr[(ROWS + r) * 9 + j];
            const float sp = fmaxf(x, 0.f) + log1pf(expf(-fabsf(x)));
            sca[r * 9 + j] = 1.0f + sp;
        }
    }

    // ---- MFMA: mixed = z @ Wm^T ; wave computes 128 rows x 32 cols ----
    f32x4 acc[8][2] = {};
#pragma unroll
    for (int m = 0; m < 8; ++m) {
        const int ar = m * 16 + lo;
        const int sx = ar & 7;
        bf16x8 af[4];
#pragma unroll
        for (int kk = 0; kk < 4; ++kk) {
            const int q0 = kk * 8 + hi * 2;
            const float4 x = *(const float4*)&zs[ar * TD + (((q0    ) ^ sx) << 2)];
            const float4 y = *(const float4*)&zs[ar * TD + (((q0 + 1) ^ sx) << 2)];
            bf16x8 f;
            f[0]=f2bf(x.x); f[1]=f2bf(x.y); f[2]=f2bf(x.z); f[3]=f2bf(x.w);
            f[4]=f2bf(y.x); f[5]=f2bf(y.y); f[6]=f2bf(y.z); f[7]=f2bf(y.w);
            af[kk] = f;
        }
#pragma unroll
        for (int n = 0; n < 2; ++n)
#pragma unroll
            for (int kk = 0; kk < 4; ++kk)
                acc[m][n] = __builtin_amdgcn_mfma_f32_16x16x32_bf16(
                                af[kk], bfr[n][kk], acc[m][n], 0, 0, 0);
    }
    __syncthreads();   // scales ready for everyone

    // ---- fused epilogue: out = z*(1+softplus) + gate*mixed ----
    const float g0 = 1.f / (1.f + expf(-gb[2 * w + 0]));
    const float g1 = 1.f / (1.f + expf(-gb[2 * w + 1]));
#pragma unroll
    for (int m = 0; m < 8; ++m) {
#pragma unroll
        for (int n = 0; n < 2; ++n) {
            const int col = w * 32 + n * 16 + lo;
            const float gg = n ? g1 : g0;
            const int cq = col >> 2, cr = col & 3;
#pragma unroll
            for (int e = 0; e < 4; ++e) {
                const int rr = m * 16 + hi * 4 + e;
                const float zv = zs[rr * TD + ((cq ^ (rr & 7)) << 2) + cr];
                const float sc = sca[rr * 9 + 2 * w + n];
                __builtin_nontemporal_store(
                    fmaf(zv, sc, gg * acc[m][n][e]),
                    &out[(row0 + rr) * TD + col]);
            }
        }
    }
}

extern "C" void kernel_launch(void* const* d_in, const int* in_sizes, int n_in,
                              void* d_out, int out_size, void* d_ws, size_t ws_size,
                              hipStream_t stream) {
    const float* z    = (const float*)d_in[0];
    const float* W1   = (const float*)d_in[1];
    const float* b1   = (const float*)d_in[2];
    const float* W2   = (const float*)d_in[3];
    const float* b2   = (const float*)d_in[4];
    const float* W3   = (const float*)d_in[5];
    const float* mixW = (const float*)d_in[6];
    const float* gb   = (const float*)d_in[7];
    float* out = (float*)d_out;

    const int B = in_sizes[0] / TD;
    soft_equiv<<<B / ROWS, 256, 0, stream>>>(z, W1, b1, W2, b2, W3, mixW, gb, out);
}

// Round 3
// 312.016 us; speedup vs baseline: 4.6048x; 1.3868x over previous
//
#include <hip/hip_runtime.h>
#include <hip/hip_bf16.h>

constexpr int NB  = 8;
constexpr int BD  = 16;
constexpr int TD  = 128;
constexpr int HID = 64;
constexpr int ROWS = 128;

typedef __attribute__((ext_vector_type(8))) short bf16x8;
typedef __attribute__((ext_vector_type(4))) float f32x4;

__device__ __forceinline__ unsigned int pk2(float a, float b) {
    __hip_bfloat162 h = __float22bfloat162_rn(float2{a, b});   // v_cvt_pk_bf16_f32 (RNE)
    unsigned int u; __builtin_memcpy(&u, &h, 4); return u;
}

// branch-free GELU: erf via Abramowitz-Stegun 7.1.26 (|err| < 1.5e-7)
__device__ __forceinline__ float gelu_fast(float x) {
    const float u = x * 0.70710678118f;
    const float a = fabsf(u);
    const float t = __builtin_amdgcn_rcpf(fmaf(0.3275911f, a, 1.0f));
    float p = fmaf(t, 1.061405429f, -1.453152027f);
    p = fmaf(t, p, 1.421413741f);
    p = fmaf(t, p, -0.284496736f);
    p = fmaf(t, p, 0.254829592f);
    p = p * t;
    const float e  = __builtin_amdgcn_exp2f(-a * a * 1.44269504f);
    const float pe = p * e;
    const float s  = (u >= 0.f) ? (2.0f - pe) : pe;   // 1 + erf(u)
    return 0.5f * x * s;
}

__global__ __launch_bounds__(256, 3)
void soft_equiv(const float* __restrict__ z,  const float* __restrict__ W1,
                const float* __restrict__ b1, const float* __restrict__ W2,
                const float* __restrict__ b2, const float* __restrict__ W3,
                const float* __restrict__ mixW, const float* __restrict__ gb,
                float* __restrict__ out)
{
    // z as bf16, 16B slots XOR-swizzled: row r, linear slot s -> slot s^(r&7)
    __shared__ __align__(16) unsigned short zs[ROWS * TD];   // 32 KB
    __shared__ float nsq[ROWS * NB];                          // 4 KB (fp32 norm^2)
    __shared__ float pscr[2 * ROWS * 9];                      // 9.2 KB
    __shared__ float sca[ROWS * 9];                           // 4.6 KB

    const int t    = threadIdx.x;
    const int lane = t & 63;
    const int w    = t >> 6;
    const int hi   = lane >> 4;
    const int lo   = lane & 15;
    const size_t row0 = (size_t)blockIdx.x * ROWS;
    const float* ztile = z + row0 * TD;

    // ---- B fragments: Wm[c][f] = mixW[i,j,d,k], c=i*16+d, f=j*16+k ----
    bf16x8 bfr[2][4];
#pragma unroll
    for (int n = 0; n < 2; ++n) {
        const int col = w * 32 + n * 16 + lo;
#pragma unroll
        for (int kk = 0; kk < 4; ++kk) {
            const int k0 = kk * 32 + hi * 8;
            const float* p = mixW + (col >> 4) * 2048 + (k0 >> 4) * 256
                                  + (col & 15) * 16 + (k0 & 15);
            const float4 x = *(const float4*)p;
            const float4 y = *(const float4*)(p + 4);
            union { unsigned int u[4]; bf16x8 v; } c;
            c.u[0] = pk2(x.x, x.y); c.u[1] = pk2(x.z, x.w);
            c.u[2] = pk2(y.x, y.y); c.u[3] = pk2(y.z, y.w);
            bfr[n][kk] = c.v;
        }
    }

    // ---- staging: global -> bf16 swizzled LDS + fp32 norm partials ----
#pragma unroll
    for (int i = 0; i < 16; ++i) {
        const int f = t + i * 256;                 // float4-chunk id in 128x128 tile
        const float4 v = *(const float4*)(ztile + 4 * f);
        const int r = f >> 5, c = f & 31;
        const int slot = (c >> 1) ^ (r & 7);
        uint2 pkd = { pk2(v.x, v.y), pk2(v.z, v.w) };
        *(uint2*)&zs[r * TD + slot * 8 + (c & 1) * 4] = pkd;
        float p = fmaf(v.x, v.x, fmaf(v.y, v.y, fmaf(v.z, v.z, v.w * v.w)));
        p += __shfl_xor(p, 1, 64);
        p += __shfl_xor(p, 2, 64);
        if ((t & 3) == 0) nsq[r * NB + (c >> 2)] = p;
    }
    __syncthreads();

    // ---- MLP: 2 threads/row, half = wave-uniform scalar ----
    const int r    = t & 127;
    const int half = __builtin_amdgcn_readfirstlane(t >> 7);

    const float4 q0 = *(const float4*)&nsq[r * NB];
    const float4 q1 = *(const float4*)&nsq[r * NB + 4];
    float nrm[NB] = { sqrtf(q0.x) + 1e-8f, sqrtf(q0.y) + 1e-8f,
                      sqrtf(q0.z) + 1e-8f, sqrtf(q0.w) + 1e-8f,
                      sqrtf(q1.x) + 1e-8f, sqrtf(q1.y) + 1e-8f,
                      sqrtf(q1.z) + 1e-8f, sqrtf(q1.w) + 1e-8f };

    float h1[HID];
#pragma unroll
    for (int i = 0; i < HID; ++i) {
        float a = b1[i];
#pragma unroll
        for (int j = 0; j < NB; ++j) a = fmaf(W1[i * NB + j], nrm[j], a);
        h1[i] = gelu_fast(a);
    }

    float acc3[NB];
#pragma unroll
    for (int j = 0; j < NB; ++j) acc3[j] = 0.f;
    const int ibase = half * 32;
#pragma unroll 2
    for (int ii = 0; ii < 32; ++ii) {
        const int i = ibase + ii;                       // scalar
        const float* w2r = W2 + i * HID;                // scalar base -> s_load
        float a0 = b2[i], a1 = 0.f, a2 = 0.f, a3 = 0.f;
#pragma unroll
        for (int j = 0; j < HID; j += 4) {
            a0 = fmaf(w2r[j + 0], h1[j + 0], a0);
            a1 = fmaf(w2r[j + 1], h1[j + 1], a1);
            a2 = fmaf(w2r[j + 2], h1[j + 2], a2);
            a3 = fmaf(w2r[j + 3], h1[j + 3], a3);
        }
        const float g = gelu_fast((a0 + a1) + (a2 + a3));
#pragma unroll
        for (int j = 0; j < NB; ++j) acc3[j] = fmaf(W3[j * HID + i], g, acc3[j]);
    }
#pragma unroll
    for (int j = 0; j < NB; ++j) pscr[(half * ROWS + r) * 9 + j] = acc3[j];
    __syncthreads();

    if (t < ROWS) {
#pragma unroll
        for (int j = 0; j < NB; ++j) {
            const float x  = pscr[t * 9 + j] + pscr[(ROWS + t) * 9 + j];
            const float sp = fmaxf(x, 0.f) + log1pf(expf(-fabsf(x)));
            sca[t * 9 + j] = 1.0f + sp;
        }
    }

    // ---- MFMA: mixed = z @ Wm^T, A-frags straight from bf16 LDS ----
    f32x4 acc[8][2] = {};
#pragma unroll
    for (int m = 0; m < 8; ++m) {
        const int ar = m * 16 + lo;
        bf16x8 af[4];
#pragma unroll
        for (int kk = 0; kk < 4; ++kk) {
            const int slot = (kk * 4 + hi) ^ (ar & 7);
            af[kk] = *(const bf16x8*)&zs[ar * TD + slot * 8];
        }
#pragma unroll
        for (int n = 0; n < 2; ++n)
#pragma unroll
            for (int kk = 0; kk < 4; ++kk)
                acc[m][n] = __builtin_amdgcn_mfma_f32_16x16x32_bf16(
                                af[kk], bfr[n][kk], acc[m][n], 0, 0, 0);
    }
    __syncthreads();   // sca ready

    // ---- epilogue: out = z*(1+softplus) + sigmoid(gate)*mixed ----
    const float g0 = 1.f / (1.f + __builtin_amdgcn_exp2f(-gb[2 * w + 0] * 1.44269504f));
    const float g1 = 1.f / (1.f + __builtin_amdgcn_exp2f(-gb[2 * w + 1] * 1.44269504f));
#pragma unroll
    for (int m = 0; m < 8; ++m) {
#pragma unroll
        for (int n = 0; n < 2; ++n) {
            const int col = w * 32 + n * 16 + lo;
            const float gg = n ? g1 : g0;
            const int sl = col >> 3, cw = col & 7;
#pragma unroll
            for (int e = 0; e < 4; ++e) {
                const int rr = m * 16 + hi * 4 + e;
                const float zv = __uint_as_float(
                    (unsigned int)zs[rr * TD + ((sl ^ (rr & 7)) * 8) + cw] << 16);
                const float sc = sca[rr * 9 + 2 * w + n];
                out[(row0 + rr) * TD + col] = fmaf(zv, sc, gg * acc[m][n][e]);
            }
        }
    }
}

extern "C" void kernel_launch(void* const* d_in, const int* in_sizes, int n_in,
                              void* d_out, int out_size, void* d_ws, size_t ws_size,
                              hipStream_t stream) {
    const float* z    = (const float*)d_in[0];
    const float* W1   = (const float*)d_in[1];
    const float* b1   = (const float*)d_in[2];
    const float* W2   = (const float*)d_in[3];
    const float* b2   = (const float*)d_in[4];
    const float* W3   = (const float*)d_in[5];
    const float* mixW = (const float*)d_in[6];
    const float* gb   = (const float*)d_in[7];
    float* out = (float*)d_out;

    const int B = in_sizes[0] / TD;
    soft_equiv<<<B / ROWS, 256, 0, stream>>>(z, W1, b1, W2, b2, W3, mixW, gb, out);
}

// Round 5
// 191.483 us; speedup vs baseline: 7.5034x; 1.6295x over previous
//
#include <hip/hip_runtime.h>
#include <hip/hip_bf16.h>

constexpr int NB  = 8;
constexpr int TD  = 128;
constexpr int HID = 64;
constexpr int ROWS = 128;

typedef __attribute__((ext_vector_type(8))) short bf16x8;
typedef __attribute__((ext_vector_type(4))) float f32x4;

union U { unsigned u[4]; bf16x8 v; };

__device__ __forceinline__ unsigned int pk2(float a, float b) {
    __hip_bfloat162 h = __float22bfloat162_rn(float2{a, b});   // v_cvt_pk_bf16_f32 (RNE)
    unsigned int u; __builtin_memcpy(&u, &h, 4); return u;
}

// branch-free GELU: erf via Abramowitz-Stegun 7.1.26 (|err| < 1.5e-7)
__device__ __forceinline__ float gelu_fast(float x) {
    const float u = x * 0.70710678118f;
    const float a = fabsf(u);
    const float t = __builtin_amdgcn_rcpf(fmaf(0.3275911f, a, 1.0f));
    float p = fmaf(t, 1.061405429f, -1.453152027f);
    p = fmaf(t, p, 1.421413741f);
    p = fmaf(t, p, -0.284496736f);
    p = fmaf(t, p, 0.254829592f);
    p = p * t;
    const float e  = __builtin_amdgcn_exp2f(-a * a * 1.44269504f);
    const float pe = p * e;
    const float s  = (u >= 0.f) ? (2.0f - pe) : pe;   // 1 + erf(u)
    return 0.5f * x * s;
}

__global__ __launch_bounds__(256, 3)
void soft_equiv(const float* __restrict__ z,  const float* __restrict__ W1,
                const float* __restrict__ b1, const float* __restrict__ W2,
                const float* __restrict__ b2, const float* __restrict__ W3,
                const float* __restrict__ mixW, const float* __restrict__ gb,
                float* __restrict__ out)
{
    __shared__ __align__(16) unsigned short zs[ROWS * TD];   // 32 KB bf16 z, swizzled
    __shared__ __align__(16) unsigned short hn[ROWS * NB];   // 2 KB bf16 norms
    __shared__ float sca[ROWS * 9];                           // 4.6 KB (1+softplus)

    const int t    = threadIdx.x;
    const int lane = t & 63;
    const int w    = t >> 6;        // wave id 0..3
    const int hi   = lane >> 4;     // 0..3
    const int lo   = lane & 15;
    const size_t row0 = (size_t)blockIdx.x * ROWS;
    const float* ztile = z + row0 * TD;
    const f32x4 z4 = {0.f, 0.f, 0.f, 0.f};

    // ================= phase 1: stage z -> bf16 swizzled LDS + fp32 norms =============
#pragma unroll
    for (int i = 0; i < 16; ++i) {
        const int f = t + i * 256;                 // float4-chunk id in 128x128 tile
        const float4 v = *(const float4*)(ztile + 4 * f);
        const int r = f >> 5, c = f & 31;
        const int slot = (c >> 1) ^ (r & 7);
        uint2 pkd = { pk2(v.x, v.y), pk2(v.z, v.w) };
        *(uint2*)&zs[r * TD + slot * 8 + (c & 1) * 4] = pkd;
        float p = fmaf(v.x, v.x, fmaf(v.y, v.y, fmaf(v.z, v.z, v.w * v.w)));
        p += __shfl_xor(p, 1, 64);
        p += __shfl_xor(p, 2, 64);
        if ((t & 3) == 0) {                        // one lane per bundle: exact fp32 norm
            const float nr = sqrtf(p) + 1e-8f;
            __hip_bfloat16 hb = __float2bfloat16(nr);
            unsigned short us; __builtin_memcpy(&us, &hb, 2);
            hn[r * NB + (c >> 2)] = us;
        }
    }

    // ============ MLP weight fragments (global, cached; overlap staging latency) ======
    // A1: W1[64][8], A-frag m=lo+16mt, k=hi*8.. (K padded to 32 with zeros)
    bf16x8 a1f[4];
#pragma unroll
    for (int mt = 0; mt < 4; ++mt) {
        U c = {};
        if (hi == 0) {
            const float4 x = *(const float4*)(W1 + (mt * 16 + lo) * NB);
            const float4 y = *(const float4*)(W1 + (mt * 16 + lo) * NB + 4);
            c.u[0] = pk2(x.x, x.y); c.u[1] = pk2(x.z, x.w);
            c.u[2] = pk2(y.x, y.y); c.u[3] = pk2(y.z, y.w);
        }
        a1f[mt] = c.v;
    }
    // A2: W2[64][64]
    bf16x8 a2f[4][2];
#pragma unroll
    for (int mt = 0; mt < 4; ++mt)
#pragma unroll
        for (int kk = 0; kk < 2; ++kk) {
            const float* p = W2 + (mt * 16 + lo) * HID + kk * 32 + hi * 8;
            const float4 x = *(const float4*)p;
            const float4 y = *(const float4*)(p + 4);
            U c;
            c.u[0] = pk2(x.x, x.y); c.u[1] = pk2(x.z, x.w);
            c.u[2] = pk2(y.x, y.y); c.u[3] = pk2(y.z, y.w);
            a2f[mt][kk] = c.v;
        }
    // A3: W3[8][64], M padded 8->16
    bf16x8 a3f[2];
#pragma unroll
    for (int kk = 0; kk < 2; ++kk) {
        U c = {};
        if (lo < NB) {
            const float* p = W3 + lo * HID + kk * 32 + hi * 8;
            const float4 x = *(const float4*)p;
            const float4 y = *(const float4*)(p + 4);
            c.u[0] = pk2(x.x, x.y); c.u[1] = pk2(x.z, x.w);
            c.u[2] = pk2(y.x, y.y); c.u[3] = pk2(y.z, y.w);
        }
        a3f[kk] = c.v;
    }
    float4 b1v[4], b2v[4];
#pragma unroll
    for (int mt = 0; mt < 4; ++mt) {
        b1v[mt] = ((const float4*)b1)[mt * 4 + hi];   // b1[mt*16+hi*4+e]
        b2v[mt] = ((const float4*)b2)[mt * 4 + hi];
    }

    __syncthreads();

    // ================= phase 2: MLP on MFMA (wave w owns rows 32w..32w+31) ============
    // L1: D1[i][r] = sum_j W1[i][j]*hn[r][j]; B1 = hn^T frag (K pad 32)
    bf16x8 b1f[2];
#pragma unroll
    for (int nt = 0; nt < 2; ++nt) {
        U c = {};
        if (hi == 0)
            c.v = *(const bf16x8*)&hn[(32 * w + nt * 16 + lo) * NB];
        b1f[nt] = c.v;
    }

    const int slA = lo + 32 * (hi & 1);   // shuffle sources for C->B handoff
    const int slB = slA + 16;
    const bool selhi = (hi & 2) != 0;

    unsigned pkh[2][4][2];                 // gelu(h1) packed, per nt/mt/pair
#pragma unroll
    for (int nt = 0; nt < 2; ++nt)
#pragma unroll
        for (int mt = 0; mt < 4; ++mt) {
            f32x4 c = __builtin_amdgcn_mfma_f32_16x16x32_bf16(a1f[mt], b1f[nt], z4, 0, 0, 0);
            const float4 bb = b1v[mt];
            const float g0 = gelu_fast(c[0] + bb.x);
            const float g1 = gelu_fast(c[1] + bb.y);
            const float g2 = gelu_fast(c[2] + bb.z);
            const float g3 = gelu_fast(c[3] + bb.w);
            pkh[nt][mt][0] = pk2(g0, g1);
            pkh[nt][mt][1] = pk2(g2, g3);
        }

    // B2[nt][kk].u[q]: j = 32kk+8hi+2q+{0,1} -> src tile 2kk+(hi>>1), src lane slA/slB
    bf16x8 b2f[2][2];
#pragma unroll
    for (int nt = 0; nt < 2; ++nt)
#pragma unroll
        for (int kk = 0; kk < 2; ++kk) {
            U c;
            const unsigned a0 = __shfl((int)pkh[nt][2*kk  ][0], slA, 64);
            const unsigned a1 = __shfl((int)pkh[nt][2*kk  ][1], slA, 64);
            const unsigned a2 = __shfl((int)pkh[nt][2*kk  ][0], slB, 64);
            const unsigned a3 = __shfl((int)pkh[nt][2*kk  ][1], slB, 64);
            const unsigned d0 = __shfl((int)pkh[nt][2*kk+1][0], slA, 64);
            const unsigned d1 = __shfl((int)pkh[nt][2*kk+1][1], slA, 64);
            const unsigned d2 = __shfl((int)pkh[nt][2*kk+1][0], slB, 64);
            const unsigned d3 = __shfl((int)pkh[nt][2*kk+1][1], slB, 64);
            c.u[0] = selhi ? d0 : a0; c.u[1] = selhi ? d1 : a1;
            c.u[2] = selhi ? d2 : a2; c.u[3] = selhi ? d3 : a3;
            b2f[nt][kk] = c.v;
        }

    // L2 + gelu + pack
    unsigned pkh2[2][4][2];
#pragma unroll
    for (int nt = 0; nt < 2; ++nt)
#pragma unroll
        for (int mt = 0; mt < 4; ++mt) {
            f32x4 c = __builtin_amdgcn_mfma_f32_16x16x32_bf16(a2f[mt][0], b2f[nt][0], z4, 0, 0, 0);
            c = __builtin_amdgcn_mfma_f32_16x16x32_bf16(a2f[mt][1], b2f[nt][1], c, 0, 0, 0);
            const float4 bb = b2v[mt];
            const float g0 = gelu_fast(c[0] + bb.x);
            const float g1 = gelu_fast(c[1] + bb.y);
            const float g2 = gelu_fast(c[2] + bb.z);
            const float g3 = gelu_fast(c[3] + bb.w);
            pkh2[nt][mt][0] = pk2(g0, g1);
            pkh2[nt][mt][1] = pk2(g2, g3);
        }

    // B3 via same handoff, L3 (M pad 16), softplus -> sca
#pragma unroll
    for (int nt = 0; nt < 2; ++nt) {
        U c0, c1;
#pragma unroll
        for (int kk = 0; kk < 2; ++kk) {
            const unsigned a0 = __shfl((int)pkh2[nt][2*kk  ][0], slA, 64);
            const unsigned a1 = __shfl((int)pkh2[nt][2*kk  ][1], slA, 64);
            const unsigned a2 = __shfl((int)pkh2[nt][2*kk  ][0], slB, 64);
            const unsigned a3 = __shfl((int)pkh2[nt][2*kk  ][1], slB, 64);
            const unsigned d0 = __shfl((int)pkh2[nt][2*kk+1][0], slA, 64);
            const unsigned d1 = __shfl((int)pkh2[nt][2*kk+1][1], slA, 64);
            const unsigned d2 = __shfl((int)pkh2[nt][2*kk+1][0], slB, 64);
            const unsigned d3 = __shfl((int)pkh2[nt][2*kk+1][1], slB, 64);
            if (kk == 0) {
                c0.u[0] = selhi ? d0 : a0; c0.u[1] = selhi ? d1 : a1;
                c0.u[2] = selhi ? d2 : a2; c0.u[3] = selhi ? d3 : a3;
            } else {
                c1.u[0] = selhi ? d0 : a0; c1.u[1] = selhi ? d1 : a1;
                c1.u[2] = selhi ? d2 : a2; c1.u[3] = selhi ? d3 : a3;
            }
        }
        f32x4 s3 = __builtin_amdgcn_mfma_f32_16x16x32_bf16(a3f[0], c0.v, z4, 0, 0, 0);
        s3 = __builtin_amdgcn_mfma_f32_16x16x32_bf16(a3f[1], c1.v, s3, 0, 0, 0);
        if (hi < 2) {                      // rows b = hi*4+e < 8 are real
            const int r = 32 * w + nt * 16 + lo;
#pragma unroll
            for (int e = 0; e < 4; ++e) {
                const float x  = s3[e];
                const float sp = fmaxf(x, 0.f) +
                    0.69314718f * __builtin_amdgcn_logf(
                        1.0f + __builtin_amdgcn_exp2f(-fabsf(x) * 1.44269504f));
                sca[r * 9 + hi * 4 + e] = 1.0f + sp;
            }
        }
    }

    // ============ mixed-einsum B fragments (issue loads before the barrier wait) ======
    bf16x8 bfr[2][4];
#pragma unroll
    for (int n = 0; n < 2; ++n) {
        const int col = w * 32 + n * 16 + lo;
#pragma unroll
        for (int kk = 0; kk < 4; ++kk) {
            const int k0 = kk * 32 + hi * 8;
            const float* p = mixW + (col >> 4) * 2048 + (k0 >> 4) * 256
                                  + (col & 15) * 16 + (k0 & 15);
            const float4 x = *(const float4*)p;
            const float4 y = *(const float4*)(p + 4);
            U c;
            c.u[0] = pk2(x.x, x.y); c.u[1] = pk2(x.z, x.w);
            c.u[2] = pk2(y.x, y.y); c.u[3] = pk2(y.z, y.w);
            bfr[n][kk] = c.v;
        }
    }
    const float g0 = 1.f / (1.f + __builtin_amdgcn_exp2f(-gb[2 * w + 0] * 1.44269504f));
    const float g1 = 1.f / (1.f + __builtin_amdgcn_exp2f(-gb[2 * w + 1] * 1.44269504f));

    __syncthreads();   // sca complete

    // ============ phase 3: mixed einsum MFMA + fused epilogue (low acc pressure) ======
#pragma unroll
    for (int m = 0; m < 8; ++m) {
        const int ar = m * 16 + lo;
        bf16x8 af[4];
#pragma unroll
        for (int kk = 0; kk < 4; ++kk) {
            const int slot = (kk * 4 + hi) ^ (ar & 7);
            af[kk] = *(const bf16x8*)&zs[ar * TD + slot * 8];
        }
#pragma unroll
        for (int n = 0; n < 2; ++n) {
            f32x4 acc = z4;
#pragma unroll
            for (int kk = 0; kk < 4; ++kk)
                acc = __builtin_amdgcn_mfma_f32_16x16x32_bf16(af[kk], bfr[n][kk], acc, 0, 0, 0);
            const int col = w * 32 + n * 16 + lo;
            const float gg = n ? g1 : g0;
            const int sl = col >> 3, cw = col & 7;
#pragma unroll
            for (int e = 0; e < 4; ++e) {
                const int rr = m * 16 + hi * 4 + e;
                const float zv = __uint_as_float(
                    (unsigned int)zs[rr * TD + ((sl ^ (rr & 7)) * 8) + cw] << 16);
                const float sc = sca[rr * 9 + 2 * w + n];
                out[(row0 + rr) * TD + col] = fmaf(zv, sc, gg * acc[e]);
            }
        }
    }
}

extern "C" void kernel_launch(void* const* d_in, const int* in_sizes, int n_in,
                              void* d_out, int out_size, void* d_ws, size_t ws_size,
                              hipStream_t stream) {
    const float* z    = (const float*)d_in[0];
    const float* W1   = (const float*)d_in[1];
    const float* b1   = (const float*)d_in[2];
    const float* W2   = (const float*)d_in[3];
    const float* b2   = (const float*)d_in[4];
    const float* W3   = (const float*)d_in[5];
    const float* mixW = (const float*)d_in[6];
    const float* gb   = (const float*)d_in[7];
    float* out = (float*)d_out;

    const int B = in_sizes[0] / TD;
    soft_equiv<<<B / ROWS, 256, 0, stream>>>(z, W1, b1, W2, b2, W3, mixW, gb, out);
}

// Round 7
// 135.008 us; speedup vs baseline: 10.6421x; 1.4183x over previous
//
#include <hip/hip_runtime.h>
#include <hip/hip_bf16.h>

constexpr int NB  = 8;
constexpr int TD  = 128;
constexpr int HID = 64;
constexpr int ROWS = 128;

typedef __attribute__((ext_vector_type(8))) short bf16x8;
typedef __attribute__((ext_vector_type(4))) float f32x4;

union U { unsigned u[4]; bf16x8 v; };

__device__ __forceinline__ unsigned int pk2(float a, float b) {
    __hip_bfloat162 h = __float22bfloat162_rn(float2{a, b});   // v_cvt_pk_bf16_f32 (RNE)
    unsigned int u; __builtin_memcpy(&u, &h, 4); return u;
}

// branch-free GELU: erf via Abramowitz-Stegun 7.1.26 (|err| < 1.5e-7)
__device__ __forceinline__ float gelu_fast(float x) {
    const float u = x * 0.70710678118f;
    const float a = fabsf(u);
    const float t = __builtin_amdgcn_rcpf(fmaf(0.3275911f, a, 1.0f));
    float p = fmaf(t, 1.061405429f, -1.453152027f);
    p = fmaf(t, p, 1.421413741f);
    p = fmaf(t, p, -0.284496736f);
    p = fmaf(t, p, 0.254829592f);
    p = p * t;
    const float e  = __builtin_amdgcn_exp2f(-a * a * 1.44269504f);
    const float pe = p * e;
    const float s  = (u >= 0.f) ? (2.0f - pe) : pe;   // 1 + erf(u)
    return 0.5f * x * s;
}

// ws layout (u32 pairs): [0,8192) mixW ; [8192,10240) W2 ; [10240,10496) W1 ; [10496,10752) W3
constexpr size_t WS_NEED_BYTES = 10752 * 4;

__global__ __launch_bounds__(256, 1)
void cvt_weights(const float* __restrict__ W1, const float* __restrict__ W2,
                 const float* __restrict__ W3, const float* __restrict__ mixW,
                 unsigned* __restrict__ ws)
{
    const int t = threadIdx.x;
#pragma unroll
    for (int i = 0; i < 32; ++i) {                 // mixW -> Wm[c][f], c=i*16+d, f=j*16+k
        const int p = t + i * 256;
        const int o = 2 * p;
        const int c = o >> 7, f = o & 127;
        const int ii = c >> 4, d = c & 15, j = f >> 4, k = f & 15;
        const float2 v = *(const float2*)(mixW + ii * 2048 + j * 256 + d * 16 + k);
        ws[p] = pk2(v.x, v.y);
    }
#pragma unroll
    for (int i = 0; i < 8; ++i) {                  // W2 row-major 64x64
        const int p = t + i * 256;
        const float2 v = *(const float2*)(W2 + 2 * p);
        ws[8192 + p] = pk2(v.x, v.y);
    }
    {
        const float2 v1 = *(const float2*)(W1 + 2 * t);   // W1 64x8
        ws[10240 + t] = pk2(v1.x, v1.y);
        const float2 v3 = *(const float2*)(W3 + 2 * t);   // W3 8x64
        ws[10496 + t] = pk2(v3.x, v3.y);
    }
}

template<bool USE_WS>
__global__ __launch_bounds__(256, 4)
void soft_equiv(const float* __restrict__ z,  const float* __restrict__ W1,
                const float* __restrict__ b1, const float* __restrict__ W2,
                const float* __restrict__ b2, const float* __restrict__ W3,
                const float* __restrict__ mixW, const float* __restrict__ gb,
                const unsigned short* __restrict__ wsu,
                float* __restrict__ out)
{
    __shared__ __align__(16) unsigned short zs[ROWS * TD];   // 32 KB bf16 z, swizzled
    __shared__ __align__(16) unsigned short hn[ROWS * NB];   // 2 KB bf16 norms
    __shared__ float sca[ROWS * 9];                           // 4.6 KB (1+softplus)

    const int t    = threadIdx.x;
    const int lane = t & 63;
    const int w    = t >> 6;        // wave id 0..3
    const int hi   = lane >> 4;     // 0..3
    const int lo   = lane & 15;
    const size_t row0 = (size_t)blockIdx.x * ROWS;
    const float* ztile = z + row0 * TD;
    const f32x4 z4 = {0.f, 0.f, 0.f, 0.f};

    // ====== phase 1: stage z -> bf16 swizzled LDS; in-register fp32 norms =======
#pragma unroll
    for (int i = 0; i < 4; ++i) {
        const int idx = t + i * 256;               // (row, bundle)
        const int r = idx >> 3, b = idx & 7;
        const float* p = ztile + r * TD + b * 16;
        const float4 v0 = *(const float4*)(p);
        const float4 v1 = *(const float4*)(p + 4);
        const float4 v2 = *(const float4*)(p + 8);
        const float4 v3 = *(const float4*)(p + 12);
        const int sw = r & 7;
        uint4 q0 = { pk2(v0.x, v0.y), pk2(v0.z, v0.w), pk2(v1.x, v1.y), pk2(v1.z, v1.w) };
        uint4 q1 = { pk2(v2.x, v2.y), pk2(v2.z, v2.w), pk2(v3.x, v3.y), pk2(v3.z, v3.w) };
        *(uint4*)&zs[r * TD + (((2 * b    ) ^ sw) * 8)] = q0;
        *(uint4*)&zs[r * TD + (((2 * b + 1) ^ sw) * 8)] = q1;
        float s0 = 0.f, s1 = 0.f, s2 = 0.f, s3 = 0.f;
        s0 = fmaf(v0.x, v0.x, s0); s1 = fmaf(v0.y, v0.y, s1);
        s2 = fmaf(v0.z, v0.z, s2); s3 = fmaf(v0.w, v0.w, s3);
        s0 = fmaf(v1.x, v1.x, s0); s1 = fmaf(v1.y, v1.y, s1);
        s2 = fmaf(v1.z, v1.z, s2); s3 = fmaf(v1.w, v1.w, s3);
        s0 = fmaf(v2.x, v2.x, s0); s1 = fmaf(v2.y, v2.y, s1);
        s2 = fmaf(v2.z, v2.z, s2); s3 = fmaf(v2.w, v2.w, s3);
        s0 = fmaf(v3.x, v3.x, s0); s1 = fmaf(v3.y, v3.y, s1);
        s2 = fmaf(v3.z, v3.z, s2); s3 = fmaf(v3.w, v3.w, s3);
        const float nr = sqrtf((s0 + s1) + (s2 + s3)) + 1e-8f;
        __hip_bfloat16 hb = __float2bfloat16(nr);
        unsigned short us; __builtin_memcpy(&us, &hb, 2);
        hn[r * NB + b] = us;
    }

    // ====== MLP weight fragments ======
    bf16x8 a1f[4];
    bf16x8 a2f[4][2];
    bf16x8 a3f[2];
    if constexpr (USE_WS) {
#pragma unroll
        for (int mt = 0; mt < 4; ++mt) {
            U c = {};
            if (hi == 0) c.v = *(const bf16x8*)(wsu + 2 * 10240 + (mt * 16 + lo) * 8);
            a1f[mt] = c.v;
        }
#pragma unroll
        for (int mt = 0; mt < 4; ++mt)
#pragma unroll
            for (int kk = 0; kk < 2; ++kk)
                a2f[mt][kk] = *(const bf16x8*)(wsu + 2 * 8192 + (mt * 16 + lo) * HID + kk * 32 + hi * 8);
#pragma unroll
        for (int kk = 0; kk < 2; ++kk) {
            U c = {};
            if (lo < NB) c.v = *(const bf16x8*)(wsu + 2 * 10496 + lo * HID + kk * 32 + hi * 8);
            a3f[kk] = c.v;
        }
    } else {
#pragma unroll
        for (int mt = 0; mt < 4; ++mt) {
            U c = {};
            if (hi == 0) {
                const float4 x = *(const float4*)(W1 + (mt * 16 + lo) * NB);
                const float4 y = *(const float4*)(W1 + (mt * 16 + lo) * NB + 4);
                c.u[0] = pk2(x.x, x.y); c.u[1] = pk2(x.z, x.w);
                c.u[2] = pk2(y.x, y.y); c.u[3] = pk2(y.z, y.w);
            }
            a1f[mt] = c.v;
        }
#pragma unroll
        for (int mt = 0; mt < 4; ++mt)
#pragma unroll
            for (int kk = 0; kk < 2; ++kk) {
                const float* p = W2 + (mt * 16 + lo) * HID + kk * 32 + hi * 8;
                const float4 x = *(const float4*)p;
                const float4 y = *(const float4*)(p + 4);
                U c;
                c.u[0] = pk2(x.x, x.y); c.u[1] = pk2(x.z, x.w);
                c.u[2] = pk2(y.x, y.y); c.u[3] = pk2(y.z, y.w);
                a2f[mt][kk] = c.v;
            }
#pragma unroll
        for (int kk = 0; kk < 2; ++kk) {
            U c = {};
            if (lo < NB) {
                const float* p = W3 + lo * HID + kk * 32 + hi * 8;
                const float4 x = *(const float4*)p;
                const float4 y = *(const float4*)(p + 4);
                c.u[0] = pk2(x.x, x.y); c.u[1] = pk2(x.z, x.w);
                c.u[2] = pk2(y.x, y.y); c.u[3] = pk2(y.z, y.w);
            }
            a3f[kk] = c.v;
        }
    }
    float4 b1v[4], b2v[4];
#pragma unroll
    for (int mt = 0; mt < 4; ++mt) {
        b1v[mt] = ((const float4*)b1)[mt * 4 + hi];
        b2v[mt] = ((const float4*)b2)[mt * 4 + hi];
    }

    __syncthreads();

    // ====== phase 2: MLP on MFMA (wave w owns rows 32w..32w+31) ======
    bf16x8 b1f[2];
#pragma unroll
    for (int nt = 0; nt < 2; ++nt) {
        U c = {};
        if (hi == 0)
            c.v = *(const bf16x8*)&hn[(32 * w + nt * 16 + lo) * NB];
        b1f[nt] = c.v;
    }

    const int slA = lo + 32 * (hi & 1);
    const int slB = slA + 16;
    const bool selhi = (hi & 2) != 0;

    unsigned pkh[2][4][2];
#pragma unroll
    for (int nt = 0; nt < 2; ++nt)
#pragma unroll
        for (int mt = 0; mt < 4; ++mt) {
            f32x4 c = __builtin_amdgcn_mfma_f32_16x16x32_bf16(a1f[mt], b1f[nt], z4, 0, 0, 0);
            const float4 bb = b1v[mt];
            const float g0 = gelu_fast(c[0] + bb.x);
            const float g1 = gelu_fast(c[1] + bb.y);
            const float g2 = gelu_fast(c[2] + bb.z);
            const float g3 = gelu_fast(c[3] + bb.w);
            pkh[nt][mt][0] = pk2(g0, g1);
            pkh[nt][mt][1] = pk2(g2, g3);
        }

    bf16x8 b2f[2][2];
#pragma unroll
    for (int nt = 0; nt < 2; ++nt)
#pragma unroll
        for (int kk = 0; kk < 2; ++kk) {
            U c;
            const unsigned a0 = __shfl((int)pkh[nt][2*kk  ][0], slA, 64);
            const unsigned a1 = __shfl((int)pkh[nt][2*kk  ][1], slA, 64);
            const unsigned a2 = __shfl((int)pkh[nt][2*kk  ][0], slB, 64);
            const unsigned a3 = __shfl((int)pkh[nt][2*kk  ][1], slB, 64);
            const unsigned d0 = __shfl((int)pkh[nt][2*kk+1][0], slA, 64);
            const unsigned d1 = __shfl((int)pkh[nt][2*kk+1][1], slA, 64);
            const unsigned d2 = __shfl((int)pkh[nt][2*kk+1][0], slB, 64);
            const unsigned d3 = __shfl((int)pkh[nt][2*kk+1][1], slB, 64);
            c.u[0] = selhi ? d0 : a0; c.u[1] = selhi ? d1 : a1;
            c.u[2] = selhi ? d2 : a2; c.u[3] = selhi ? d3 : a3;
            b2f[nt][kk] = c.v;
        }

    unsigned pkh2[2][4][2];
#pragma unroll
    for (int nt = 0; nt < 2; ++nt)
#pragma unroll
        for (int mt = 0; mt < 4; ++mt) {
            f32x4 c = __builtin_amdgcn_mfma_f32_16x16x32_bf16(a2f[mt][0], b2f[nt][0], z4, 0, 0, 0);
            c = __builtin_amdgcn_mfma_f32_16x16x32_bf16(a2f[mt][1], b2f[nt][1], c, 0, 0, 0);
            const float4 bb = b2v[mt];
            const float g0 = gelu_fast(c[0] + bb.x);
            const float g1 = gelu_fast(c[1] + bb.y);
            const float g2 = gelu_fast(c[2] + bb.z);
            const float g3 = gelu_fast(c[3] + bb.w);
            pkh2[nt][mt][0] = pk2(g0, g1);
            pkh2[nt][mt][1] = pk2(g2, g3);
        }

#pragma unroll
    for (int nt = 0; nt < 2; ++nt) {
        U c0, c1;
#pragma unroll
        for (int kk = 0; kk < 2; ++kk) {
            const unsigned a0 = __shfl((int)pkh2[nt][2*kk  ][0], slA, 64);
            const unsigned a1 = __shfl((int)pkh2[nt][2*kk  ][1], slA, 64);
            const unsigned a2 = __shfl((int)pkh2[nt][2*kk  ][0], slB, 64);
            const unsigned a3 = __shfl((int)pkh2[nt][2*kk  ][1], slB, 64);
            const unsigned d0 = __shfl((int)pkh2[nt][2*kk+1][0], slA, 64);
            const unsigned d1 = __shfl((int)pkh2[nt][2*kk+1][1], slA, 64);
            const unsigned d2 = __shfl((int)pkh2[nt][2*kk+1][0], slB, 64);
            const unsigned d3 = __shfl((int)pkh2[nt][2*kk+1][1], slB, 64);
            if (kk == 0) {
                c0.u[0] = selhi ? d0 : a0; c0.u[1] = selhi ? d1 : a1;
                c0.u[2] = selhi ? d2 : a2; c0.u[3] = selhi ? d3 : a3;
            } else {
                c1.u[0] = selhi ? d0 : a0; c1.u[1] = selhi ? d1 : a1;
                c1.u[2] = selhi ? d2 : a2; c1.u[3] = selhi ? d3 : a3;
            }
        }
        f32x4 s3 = __builtin_amdgcn_mfma_f32_16x16x32_bf16(a3f[0], c0.v, z4, 0, 0, 0);
        s3 = __builtin_amdgcn_mfma_f32_16x16x32_bf16(a3f[1], c1.v, s3, 0, 0, 0);
        if (hi < 2) {
            const int r = 32 * w + nt * 16 + lo;
#pragma unroll
            for (int e = 0; e < 4; ++e) {
                const float x  = s3[e];
                const float sp = fmaxf(x, 0.f) +
                    0.69314718f * __builtin_amdgcn_logf(
                        1.0f + __builtin_amdgcn_exp2f(-fabsf(x) * 1.44269504f));
                sca[r * 9 + hi * 4 + e] = 1.0f + sp;
            }
        }
    }

    // ====== mixed-einsum B fragments ======
    bf16x8 bfr[2][4];
#pragma unroll
    for (int n = 0; n < 2; ++n) {
        const int col = w * 32 + n * 16 + lo;
#pragma unroll
        for (int kk = 0; kk < 4; ++kk) {
            if constexpr (USE_WS) {
                bfr[n][kk] = *(const bf16x8*)(wsu + col * TD + kk * 32 + hi * 8);
            } else {
                const int k0 = kk * 32 + hi * 8;
                const float* p = mixW + (col >> 4) * 2048 + (k0 >> 4) * 256
                                      + (col & 15) * 16 + (k0 & 15);
                const float4 x = *(const float4*)p;
                const float4 y = *(const float4*)(p + 4);
                U c;
                c.u[0] = pk2(x.x, x.y); c.u[1] = pk2(x.z, x.w);
                c.u[2] = pk2(y.x, y.y); c.u[3] = pk2(y.z, y.w);
                bfr[n][kk] = c.v;
            }
        }
    }
    const float g0 = 1.f / (1.f + __builtin_amdgcn_exp2f(-gb[2 * w + 0] * 1.44269504f));
    const float g1 = 1.f / (1.f + __builtin_amdgcn_exp2f(-gb[2 * w + 1] * 1.44269504f));

    __syncthreads();   // sca complete

    // ====== phase 3: mixed einsum MFMA + fused epilogue ======
#pragma unroll
    for (int m = 0; m < 8; ++m) {
        const int ar = m * 16 + lo;
        bf16x8 af[4];
#pragma unroll
        for (int kk = 0; kk < 4; ++kk) {
            const int slot = (kk * 4 + hi) ^ (ar & 7);
            af[kk] = *(const bf16x8*)&zs[ar * TD + slot * 8];
        }
#pragma unroll
        for (int n = 0; n < 2; ++n) {
            f32x4 acc = z4;
#pragma unroll
            for (int kk = 0; kk < 4; ++kk)
                acc = __builtin_amdgcn_mfma_f32_16x16x32_bf16(af[kk], bfr[n][kk], acc, 0, 0, 0);
            const int col = w * 32 + n * 16 + lo;
            const float gg = n ? g1 : g0;
            const int sl = col >> 3, cw = col & 7;
#pragma unroll
            for (int e = 0; e < 4; ++e) {
                const int rr = m * 16 + hi * 4 + e;
                const float zv = __uint_as_float(
                    (unsigned int)zs[rr * TD + ((sl ^ (rr & 7)) * 8) + cw] << 16);
                const float sc = sca[rr * 9 + 2 * w + n];
                out[(row0 + rr) * TD + col] = fmaf(zv, sc, gg * acc[e]);
            }
        }
    }
}

extern "C" void kernel_launch(void* const* d_in, const int* in_sizes, int n_in,
                              void* d_out, int out_size, void* d_ws, size_t ws_size,
                              hipStream_t stream) {
    const float* z    = (const float*)d_in[0];
    const float* W1   = (const float*)d_in[1];
    const float* b1   = (const float*)d_in[2];
    const float* W2   = (const float*)d_in[3];
    const float* b2   = (const float*)d_in[4];
    const float* W3   = (const float*)d_in[5];
    const float* mixW = (const float*)d_in[6];
    const float* gb   = (const float*)d_in[7];
    float* out = (float*)d_out;

    const int B = in_sizes[0] / TD;
    if (ws_size >= WS_NEED_BYTES && d_ws != nullptr) {
        cvt_weights<<<1, 256, 0, stream>>>(W1, W2, W3, mixW, (unsigned*)d_ws);
        soft_equiv<true><<<B / ROWS, 256, 0, stream>>>(
            z, W1, b1, W2, b2, W3, mixW, gb, (const unsigned short*)d_ws, out);
    } else {
        soft_equiv<false><<<B / ROWS, 256, 0, stream>>>(
            z, W1, b1, W2, b2, W3, mixW, gb, nullptr, out);
    }
}